// Round 10
// baseline (135.747 us; speedup 1.0000x reference)
//
#include <hip/hip_runtime.h>

#define DIN 768

typedef float f2 __attribute__((ext_vector_type(2)));
typedef int i2v __attribute__((ext_vector_type(2)));

#if __has_builtin(__builtin_amdgcn_permlane32_swap)
#define HAVE_PL32 1
#endif
#if __has_builtin(__builtin_amdgcn_permlane16_swap)
#define HAVE_PL16 1
#endif

__device__ __forceinline__ int f2i(float v) { return __builtin_bit_cast(int, v); }
__device__ __forceinline__ float i2f(int v) { return __builtin_bit_cast(float, v); }

// DPP ctrl: quad_perm xor1 = 0xB1 ; xor2 = 0x4E ; row_ror:4 = 0x124 ; row_ror:8 = 0x128
template<int CTRL>
__device__ __forceinline__ float dppf(float v) {
  const int i = f2i(v);
  return i2f(__builtin_amdgcn_update_dpp(i, i, CTRL, 0xF, 0xF, true));
}
template<int CTRL>
__device__ __forceinline__ f2 dppf2(f2 v) {
  f2 r; r.x = dppf<CTRL>(v.x); r.y = dppf<CTRL>(v.y); return r;
}

// Full 64-lane sum of both f2 components. Zero DS ops. (Used once, for sumsq.)
__device__ __forceinline__ f2 wsum2(f2 v) {
  v += dppf2<0xB1>(v);
  v += dppf2<0x4E>(v);
  v += dppf2<0x124>(v);
  v += dppf2<0x128>(v);
#ifdef HAVE_PL16
  { i2v rx = __builtin_amdgcn_permlane16_swap(f2i(v.x), f2i(v.x), false, false);
    i2v ry = __builtin_amdgcn_permlane16_swap(f2i(v.y), f2i(v.y), false, false);
    v.x = i2f(rx.x) + i2f(rx.y);
    v.y = i2f(ry.x) + i2f(ry.y); }
#else
  v.x += __shfl_xor(v.x, 16); v.y += __shfl_xor(v.y, 16);
#endif
#ifdef HAVE_PL32
  { i2v rx = __builtin_amdgcn_permlane32_swap(f2i(v.x), f2i(v.x), false, false);
    i2v ry = __builtin_amdgcn_permlane32_swap(f2i(v.y), f2i(v.y), false, false);
    v.x = i2f(rx.x) + i2f(rx.y);
    v.y = i2f(ry.x) + i2f(ry.y); }
#else
  v.x += __shfl_xor(v.x, 32); v.y += __shfl_xor(v.y, 32);
#endif
  return v;
}

// ds_swizzle xor4 (lane ^ 4) for expval q5
__device__ __forceinline__ f2 swz4_f2(f2 v) {
  f2 r;
  r.x = i2f(__builtin_amdgcn_ds_swizzle(f2i(v.x), 0x101F));   // xor=4, and=0x1F
  r.y = i2f(__builtin_amdgcn_ds_swizzle(f2i(v.y), 0x101F));
  return r;
}

// LDS address swizzle (bijective involution on 0..1023 f2 cells)
__device__ __forceinline__ int swz(int j) { return j ^ ((j >> 4) & 15); }

// Composite gather map of the CNOT ring CNOT(0,1)..CNOT(9,0): Final[i] = In[cnotL(i)]
__device__ __forceinline__ int cnotL(int i) {
  const int b9 = (i >> 9) & 1;
  const int b8 = (i >> 8) & 1;
  const int b0 = i & 1;
  return ((i ^ (i >> 1)) & 0xFF) | ((b8 ^ b9 ^ b0) << 8) | ((b9 ^ b0) << 9);
}

// Layout-B bit permutation of the superlane (sl = (h<<6)|lane):
// i = (r<<7) | bmap(sl) with  l1->i6, l0->i5, l2->i4, l3->i3, l4->i2, l5->i1, h->i0
// so qubits at B: q0,1,2 = r bits 2,1,0 ; q3 = lane bit1 (dpp mask2) ; q4 = lane bit0
// (dpp mask1) ; q5 = lane bit2 (ds_swizzle xor4) ; q9 = wave bit (never gated at B).
__device__ __forceinline__ int bmap(int sl) {
  const int l = sl & 63, h = sl >> 6;
  return (((l >> 1) & 1) << 6) | ((l & 1) << 5) | (((l >> 2) & 1) << 4) |
         (((l >> 3) & 1) << 3) | (((l >> 4) & 1) << 2) | (((l >> 5) & 1) << 1) | h;
}

// RY on an 8-reg f2 array (rows packed). RB in {0,1,2}.
template<int RB>
__device__ __forceinline__ void ry8(f2 (&a)[8], float c, float s) {
#pragma unroll
  for (int r = 0; r < 8; ++r) {
    if (!(r & (1 << RB))) {
      const int p = r | (1 << RB);
      const f2 a0 = a[r], a1 = a[p];
      a[r] = a0 * c - a1 * s;
      a[p] = a1 * c + a0 * s;
    }
  }
}
// RY via DPP lane partner; ssgn = (lane&mask)? s : -s (precomputed)
template<int CTRL>
__device__ __forceinline__ void ry8_dpp(f2 (&a)[8], float c, float ssgn) {
#pragma unroll
  for (int r = 0; r < 8; ++r) {
    const f2 p = dppf2<CTRL>(a[r]);
    a[r] = a[r] * c + p * ssgn;
  }
}

// ---------------- prep kernel: all weight-dependent transcendentals ----------------
// ws layout (float2): [0..69] gate table; [70..1093] rz1 (B-layout-permuted, linear
// index k=(r<<7)|sl holds phase of amp (r<<7)|bmap(sl)); [1094..2117] rz2 likewise.
__global__ void qae_prep(const float* __restrict__ w, float2* __restrict__ ws) {
  const int k = threadIdx.x;          // 0..1023
  if (k < 50) {                       // half-angle gate coefficients
    float s, c; __sincosf(0.5f * w[k], &s, &c);
    ws[k] = make_float2(c, s);
  } else if (k < 56) {                // FULL angle: Heisenberg output transform w[50..55]
    float s, c; __sincosf(w[k], &s, &c);
    ws[k] = make_float2(c, s);
  } else if (k < 60) {
    ws[k] = make_float2(1.f, 0.f);    // unused
  } else if (k < 70) {                // folded RY_b(layer1)+RY_c(layer2)
    const int q = k - 60;
    float s, c; __sincosf(0.5f * (w[20 + q] + w[30 + q]), &s, &c);
    ws[60 + q] = make_float2(c, s);
  }
  const int r  = k >> 7, sl = k & 127;
  const int i  = (r << 7) | bmap(sl);
  float p1 = 0.f, p2 = 0.f;
#pragma unroll
  for (int b = 0; b < 10; ++b) {
    const float sg = ((i >> b) & 1) ? 0.5f : -0.5f;
    p1 += sg * w[10 + 9 - b];
    p2 += sg * w[40 + 9 - b];
  }
  float s, c;
  __sincosf(p1, &s, &c); ws[70 + k]        = make_float2(c, s);
  __sincosf(p2, &s, &c); ws[70 + 1024 + k] = make_float2(c, s);
}

// -------- main kernel: 128 threads = 2 waves co-owning one row-pair (f2-packed) --------
// Layout A: amp i = (sl<<3)|r  -> q0=wave bit, q1..q6=lane bits 5..0, q7,8,9=r bits 2,1,0
// Layout B: amp i = (r<<7)|bmap(sl)  (see bmap)
__global__ __launch_bounds__(128, 8) void qae_main(const float* __restrict__ x,
                                                   const float2* __restrict__ gt,
                                                   float* __restrict__ out, int Btot) {
  __shared__ f2 st[1026];               // 8KB transpose buffer + 2 sumsq slots
  const int sl   = threadIdx.x;         // superlane 0..127
  const int lane = sl & 63;
  const int h    = sl >> 6;
  const int b0   = blockIdx.x * 2;
  const bool has1 = (b0 + 1 < Btot);
  const int bm   = bmap(sl);
  const int base = sl << 3;             // layout-A amp base
  const float2* rz1 = gt + 70;
  const float2* rz2 = gt + 70 + 1024;

  // ---- load rows (layout A), amps >= 768 zero (sl >= 96)
  f2 re[8], im[8];
  f2 ss = (f2){0.f, 0.f};
  const float* x0 = x + (size_t)b0 * DIN;
  const float* x1 = x + (size_t)(b0 + 1) * DIN;
#pragma unroll
  for (int t = 0; t < 2; ++t) {
    const int idx = base + 4 * t;
    float4 va = make_float4(0.f, 0.f, 0.f, 0.f);
    float4 vb = make_float4(0.f, 0.f, 0.f, 0.f);
    if (idx < DIN) {
      va = *reinterpret_cast<const float4*>(x0 + idx);
      if (has1) vb = *reinterpret_cast<const float4*>(x1 + idx);
    }
    re[4*t+0] = (f2){va.x, vb.x}; re[4*t+1] = (f2){va.y, vb.y};
    re[4*t+2] = (f2){va.z, vb.z}; re[4*t+3] = (f2){va.w, vb.w};
#pragma unroll
    for (int k = 0; k < 4; ++k) ss += re[4*t+k] * re[4*t+k];
  }
  ss = wsum2(ss);                        // per-wave partial (its 512 amps, both rows)
  if (lane == 0) st[1024 + h] = ss;

  float2 cs;
  // ===== round 1 RY (w[0..9]) — REAL state. A-part: q7,q8,q9 reg; q5,q6 dpp =====
  cs = gt[7]; ry8<2>(re, cs.x, cs.y);
  cs = gt[8]; ry8<1>(re, cs.x, cs.y);
  cs = gt[9]; ry8<0>(re, cs.x, cs.y);
  cs = gt[5]; ry8_dpp<0x4E>(re, cs.x, (lane & 2) ? cs.y : -cs.y);
  cs = gt[6]; ry8_dpp<0xB1>(re, cs.x, (lane & 1) ? cs.y : -cs.y);

  // T1: A->B (real, 1 pass)
#pragma unroll
  for (int r = 0; r < 8; ++r) st[swz(base + r)] = re[r];
  __syncthreads();
#pragma unroll
  for (int r = 0; r < 8; ++r) re[r] = st[swz((r << 7) | bm)];
  __syncthreads();

  // B-part: q0,q1,q2 reg; q3,q4 dpp
  cs = gt[0]; ry8<2>(re, cs.x, cs.y);
  cs = gt[1]; ry8<1>(re, cs.x, cs.y);
  cs = gt[2]; ry8<0>(re, cs.x, cs.y);
  cs = gt[3]; ry8_dpp<0x4E>(re, cs.x, (lane & 2) ? cs.y : -cs.y);
  cs = gt[4]; ry8_dpp<0xB1>(re, cs.x, (lane & 1) ? cs.y : -cs.y);

  // RZ1 (permuted table): real -> complex
#pragma unroll
  for (int r = 0; r < 8; ++r) {
    const float2 t = rz1[(r << 7) | sl];
    im[r] = re[r] * t.y;
    re[r] = re[r] * t.x;
  }

  // T2: CNOT ring 1 (write B, gather-read into A), 2 passes
#pragma unroll
  for (int r = 0; r < 8; ++r) st[swz((r << 7) | bm)] = re[r];
  __syncthreads();
#pragma unroll
  for (int r = 0; r < 8; ++r) re[r] = st[swz(cnotL(base + r))];
  __syncthreads();
#pragma unroll
  for (int r = 0; r < 8; ++r) st[swz((r << 7) | bm)] = im[r];
  __syncthreads();
#pragma unroll
  for (int r = 0; r < 8; ++r) im[r] = st[swz(cnotL(base + r))];
  __syncthreads();

  // ===== combined RY (folded RY_b1+RY_c2, gt[60..69]). A-part: q7,8,9 reg; q5,q6 dpp =====
  cs = gt[67]; ry8<2>(re, cs.x, cs.y); ry8<2>(im, cs.x, cs.y);
  cs = gt[68]; ry8<1>(re, cs.x, cs.y); ry8<1>(im, cs.x, cs.y);
  cs = gt[69]; ry8<0>(re, cs.x, cs.y); ry8<0>(im, cs.x, cs.y);
  { cs = gt[65]; const float sg = (lane & 2) ? cs.y : -cs.y;
    ry8_dpp<0x4E>(re, cs.x, sg); ry8_dpp<0x4E>(im, cs.x, sg); }
  { cs = gt[66]; const float sg = (lane & 1) ? cs.y : -cs.y;
    ry8_dpp<0xB1>(re, cs.x, sg); ry8_dpp<0xB1>(im, cs.x, sg); }

  // T3: A->B plain, 2 passes
#pragma unroll
  for (int r = 0; r < 8; ++r) st[swz(base + r)] = re[r];
  __syncthreads();
#pragma unroll
  for (int r = 0; r < 8; ++r) re[r] = st[swz((r << 7) | bm)];
  __syncthreads();
#pragma unroll
  for (int r = 0; r < 8; ++r) st[swz(base + r)] = im[r];
  __syncthreads();
#pragma unroll
  for (int r = 0; r < 8; ++r) im[r] = st[swz((r << 7) | bm)];
  __syncthreads();

  // B-part: q0,q1,q2 reg; q3,q4 dpp
  cs = gt[60]; ry8<2>(re, cs.x, cs.y); ry8<2>(im, cs.x, cs.y);
  cs = gt[61]; ry8<1>(re, cs.x, cs.y); ry8<1>(im, cs.x, cs.y);
  cs = gt[62]; ry8<0>(re, cs.x, cs.y); ry8<0>(im, cs.x, cs.y);
  { cs = gt[63]; const float sg = (lane & 2) ? cs.y : -cs.y;
    ry8_dpp<0x4E>(re, cs.x, sg); ry8_dpp<0x4E>(im, cs.x, sg); }
  { cs = gt[64]; const float sg = (lane & 1) ? cs.y : -cs.y;
    ry8_dpp<0xB1>(re, cs.x, sg); ry8_dpp<0xB1>(im, cs.x, sg); }

  // RZ2 (permuted table)
#pragma unroll
  for (int r = 0; r < 8; ++r) {
    const float2 t = rz2[(r << 7) | sl];
    const f2 nre = re[r] * t.x - im[r] * t.y;
    im[r] = re[r] * t.y + im[r] * t.x;
    re[r] = nre;
  }

  // T4: CNOT ring 2 (write B, gather-read back into B), 2 passes
#pragma unroll
  for (int r = 0; r < 8; ++r) st[swz((r << 7) | bm)] = re[r];
  __syncthreads();
#pragma unroll
  for (int r = 0; r < 8; ++r) re[r] = st[swz(cnotL((r << 7) | bm))];
  __syncthreads();
#pragma unroll
  for (int r = 0; r < 8; ++r) st[swz((r << 7) | bm)] = im[r];
  __syncthreads();
#pragma unroll
  for (int r = 0; r < 8; ++r) im[r] = st[swz(cnotL((r << 7) | bm))];
  __syncthreads();

  // ===== expvals at B; incremental quad-reduce flush to LDS =====
  // red float addr = q*40 + 2*j + c  (q = quad 0..31, j = obs 0..17, c = row)
  const int q16 = (h << 4) | (lane >> 2);
  auto flush = [&](int j, f2 v) {
    v += dppf2<0xB1>(v);
    v += dppf2<0x4E>(v);
    if (!(lane & 3)) st[q16 * 20 + j] = v;
  };
  const float s3 = (lane & 2) ? -1.f : 1.f;   // q3: i bit6 = lane bit1
  const float s4 = (lane & 1) ? -1.f : 1.f;   // q4: i bit5 = lane bit0
  const float s5 = (lane & 4) ? -1.f : 1.f;   // q5: i bit4 = lane bit2

  { // Z block
    f2 psum = (f2){0.f,0.f}, z0 = psum, z1 = psum, z2 = psum;
#pragma unroll
    for (int r = 0; r < 8; ++r) {
      const f2 p = re[r] * re[r] + im[r] * im[r];
      psum += p;
      z0 += (r & 4) ? -p : p;
      z1 += (r & 2) ? -p : p;
      z2 += (r & 1) ? -p : p;
    }
    flush(12, z0); flush(13, z1); flush(14, z2);
    flush(15, psum * s3); flush(16, psum * s4); flush(17, psum * s5);
  }
  { // q0: pairs r^4
    f2 aX = (f2){0.f,0.f}, aY = aX;
#pragma unroll
    for (int r = 0; r < 4; ++r) {
      const int p = r + 4;
      aX += re[r] * re[p] + im[r] * im[p];
      aY += re[r] * im[p] - im[r] * re[p];
    }
    flush(0, aX); flush(6, aY);
  }
  { // q1: pairs r^2
    f2 aX = (f2){0.f,0.f}, aY = aX;
#pragma unroll
    for (int r = 0; r < 8; ++r) if (!(r & 2)) {
      const int p = r | 2;
      aX += re[r] * re[p] + im[r] * im[p];
      aY += re[r] * im[p] - im[r] * re[p];
    }
    flush(1, aX); flush(7, aY);
  }
  { // q2: pairs r^1
    f2 aX = (f2){0.f,0.f}, aY = aX;
#pragma unroll
    for (int r = 0; r < 8; ++r) if (!(r & 1)) {
      const int p = r | 1;
      aX += re[r] * re[p] + im[r] * im[p];
      aY += re[r] * im[p] - im[r] * re[p];
    }
    flush(2, aX); flush(8, aY);
  }
  { // q3: dpp mask2 partner (double-counted)
    f2 aX = (f2){0.f,0.f}, aY = aX;
    const f2 sy = (f2){s3, s3};
#pragma unroll
    for (int r = 0; r < 8; ++r) {
      const f2 pre = dppf2<0x4E>(re[r]);
      const f2 pim = dppf2<0x4E>(im[r]);
      aX += re[r] * pre + im[r] * pim;
      aY += (re[r] * pim - im[r] * pre) * sy;
    }
    flush(3, aX); flush(9, aY);
  }
  { // q4: dpp mask1
    f2 aX = (f2){0.f,0.f}, aY = aX;
    const f2 sy = (f2){s4, s4};
#pragma unroll
    for (int r = 0; r < 8; ++r) {
      const f2 pre = dppf2<0xB1>(re[r]);
      const f2 pim = dppf2<0xB1>(im[r]);
      aX += re[r] * pre + im[r] * pim;
      aY += (re[r] * pim - im[r] * pre) * sy;
    }
    flush(4, aX); flush(10, aY);
  }
  { // q5: ds_swizzle xor4
    f2 aX = (f2){0.f,0.f}, aY = aX;
    const f2 sy = (f2){s5, s5};
#pragma unroll
    for (int r = 0; r < 8; ++r) {
      const f2 pre = swz4_f2(re[r]);
      const f2 pim = swz4_f2(im[r]);
      aX += re[r] * pre + im[r] * pim;
      aY += (re[r] * pim - im[r] * pre) * sy;
    }
    flush(5, aX); flush(11, aY);
  }
  __syncthreads();

  // ---- epilogue: 36 threads, one (row c, obs j) each; Heisenberg fold of w[50..55]
  if (sl < 36) {
    const int c  = (sl >= 18) ? 1 : 0;
    const int j  = sl - 18 * c;
    const int jq = (j < 6) ? j : ((j < 12) ? j - 6 : j - 12);
    const int jp = (j < 6) ? (j + 12) : ((j >= 12) ? (j - 12) : j);
    const float* red = reinterpret_cast<const float*>(st);
    float S = 0.f, P = 0.f;
#pragma unroll
    for (int q = 0; q < 32; ++q) {
      S += red[q * 40 + 2 * j  + c];
      P += red[q * 40 + 2 * jp + c];
    }
    const float fac = (jq < 3) ? 2.f : 1.f;   // r-pairs counted once; dpp/swizzle twice
    const float2 fa = gt[50 + jq];
    const f2 t0 = st[1024], t1 = st[1025];
    const float tot = c ? (t0.y + t1.y) : (t0.x + t1.x);
    const float inv = 1.f / fmaxf(tot, 1e-16f);
    float o;
    if (j < 6)       o = (fac * S * fa.x + P * fa.y) * inv;        // X' = c·X + s·Z
    else if (j < 12) o = fac * S * inv;                            // Y' = Y
    else             o = (S * fa.x - fac * P * fa.y) * inv;        // Z' = c·Z - s·X
    if (c == 0 || has1) out[(size_t)(b0 + c) * 18 + j] = o;
  }
}

extern "C" void kernel_launch(void* const* d_in, const int* in_sizes, int n_in,
                              void* d_out, int out_size, void* d_ws, size_t ws_size,
                              hipStream_t stream) {
  const float* x = (const float*)d_in[0];
  const float* w = (const float*)d_in[1];
  float* out = (float*)d_out;
  float2* ws = (float2*)d_ws;
  const int B = in_sizes[0] / DIN;
  qae_prep<<<dim3(1), dim3(1024), 0, stream>>>(w, ws);
  const int grid = (B + 1) / 2;      // 1 block (2 waves) per row-pair
  qae_main<<<dim3(grid), dim3(128), 0, stream>>>(x, (const float2*)ws, out, B);
}

// Round 11
// 101.690 us; speedup vs baseline: 1.3349x; 1.3349x over previous
//
#include <hip/hip_runtime.h>

#define DIN 768

typedef float f2 __attribute__((ext_vector_type(2)));
typedef int i2v __attribute__((ext_vector_type(2)));

#if __has_builtin(__builtin_amdgcn_permlane32_swap)
#define HAVE_PL32 1
#endif
#if __has_builtin(__builtin_amdgcn_permlane16_swap)
#define HAVE_PL16 1
#endif

__device__ __forceinline__ int f2i(float v) { return __builtin_bit_cast(int, v); }
__device__ __forceinline__ float i2f(int v) { return __builtin_bit_cast(float, v); }

// DPP ctrl: quad_perm xor1 = 0xB1 ; xor2 = 0x4E ; row_ror:4 = 0x124 ; row_ror:8 = 0x128
template<int CTRL>
__device__ __forceinline__ float dppf(float v) {
  const int i = f2i(v);
  return i2f(__builtin_amdgcn_update_dpp(i, i, CTRL, 0xF, 0xF, true));
}
template<int CTRL>
__device__ __forceinline__ f2 dppf2(f2 v) {
  f2 r; r.x = dppf<CTRL>(v.x); r.y = dppf<CTRL>(v.y); return r;
}

// Full 64-lane sum of both f2 components. Zero DS ops. (Used once, for sumsq.)
__device__ __forceinline__ f2 wsum2(f2 v) {
  v += dppf2<0xB1>(v);
  v += dppf2<0x4E>(v);
  v += dppf2<0x124>(v);
  v += dppf2<0x128>(v);
#ifdef HAVE_PL16
  { i2v rx = __builtin_amdgcn_permlane16_swap(f2i(v.x), f2i(v.x), false, false);
    i2v ry = __builtin_amdgcn_permlane16_swap(f2i(v.y), f2i(v.y), false, false);
    v.x = i2f(rx.x) + i2f(rx.y);
    v.y = i2f(ry.x) + i2f(ry.y); }
#else
  v.x += __shfl_xor(v.x, 16); v.y += __shfl_xor(v.y, 16);
#endif
#ifdef HAVE_PL32
  { i2v rx = __builtin_amdgcn_permlane32_swap(f2i(v.x), f2i(v.x), false, false);
    i2v ry = __builtin_amdgcn_permlane32_swap(f2i(v.y), f2i(v.y), false, false);
    v.x = i2f(rx.x) + i2f(rx.y);
    v.y = i2f(ry.x) + i2f(ry.y); }
#else
  v.x += __shfl_xor(v.x, 32); v.y += __shfl_xor(v.y, 32);
#endif
  return v;
}

// xor-shuffle of an f2, VALU-only for masks 1,2,16,32.
template<int MASK>
__device__ __forceinline__ f2 shflx_f2(f2 v, int lane) {
  f2 r;
  if constexpr (MASK == 1) {
    r = dppf2<0xB1>(v);
  } else if constexpr (MASK == 2) {
    r = dppf2<0x4E>(v);
  } else if constexpr (MASK == 16) {
#ifdef HAVE_PL16
    const i2v a = __builtin_amdgcn_permlane16_swap(f2i(v.x), f2i(v.x), false, false);
    const i2v b = __builtin_amdgcn_permlane16_swap(f2i(v.y), f2i(v.y), false, false);
    const bool hi = (lane >> 4) & 1;
    r.x = hi ? i2f(a.x) : i2f(a.y);
    r.y = hi ? i2f(b.x) : i2f(b.y);
#else
    r.x = __shfl_xor(v.x, 16); r.y = __shfl_xor(v.y, 16);
#endif
  } else if constexpr (MASK == 32) {
#ifdef HAVE_PL32
    const i2v a = __builtin_amdgcn_permlane32_swap(f2i(v.x), f2i(v.x), false, false);
    const i2v b = __builtin_amdgcn_permlane32_swap(f2i(v.y), f2i(v.y), false, false);
    const bool lo = lane < 32;
    r.x = lo ? i2f(a.y) : i2f(a.x);
    r.y = lo ? i2f(b.y) : i2f(b.x);
#else
    r.x = __shfl_xor(v.x, 32); r.y = __shfl_xor(v.y, 32);
#endif
  } else {
    r.x = __shfl_xor(v.x, MASK); r.y = __shfl_xor(v.y, MASK);
  }
  return r;
}

// LDS address swizzle (GF(2)-linear: swzf(a^b) = swzf(a)^swzf(b))
__device__ __forceinline__ int swzf(int i) { return i ^ ((i >> 4) & 31); }

// Composite gather map of the CNOT ring CNOT(0,1)..CNOT(9,0): Final[i] = In[cnotL(i)]
// GF(2)-linear: every output bit is an XOR of input bits.
__device__ __forceinline__ int cnotL(int i) {
  const int b9 = (i >> 9) & 1;
  const int b8 = (i >> 8) & 1;
  const int b0 = i & 1;
  return ((i ^ (i >> 1)) & 0xFF) | ((b8 ^ b9 ^ b0) << 8) | ((b9 ^ b0) << 9);
}

// RY on a 16-reg component array (rows packed in f2). Real 2x2 acts per component.
template<int RB>
__device__ __forceinline__ void ry1(f2 (&a)[16], float c, float s) {
#pragma unroll
  for (int r = 0; r < 16; ++r) {
    if (!(r & (1 << RB))) {
      const int p = r | (1 << RB);
      const f2 a0 = a[r], a1 = a[p];
      a[r] = a0 * c - a1 * s;
      a[p] = a1 * c + a0 * s;
    }
  }
}
template<int RB>
__device__ __forceinline__ void ry2(f2 (&re)[16], f2 (&im)[16], float c, float s) {
  ry1<RB>(re, c, s);
  ry1<RB>(im, c, s);
}
template<int MASK>
__device__ __forceinline__ void ry1_shfl(int lane, f2 (&a)[16], float c, float s) {
  const float ss = (lane & MASK) ? s : -s;
#pragma unroll
  for (int r = 0; r < 16; ++r) {
    const f2 p = shflx_f2<MASK>(a[r], lane);
    a[r] = a[r] * c + p * ss;
  }
}

// X/Y accumulate, register-pair qubit (each unordered pair once -> fac 2 at output)
template<int RB>
__device__ __forceinline__ void xyr(const f2 (&re)[16], const f2 (&im)[16], f2& aX, f2& aY) {
#pragma unroll
  for (int r = 0; r < 16; ++r) {
    if (!(r & (1 << RB))) {
      const int p = r | (1 << RB);
      aX += re[r] * re[p] + im[r] * im[p];
      aY += re[r] * im[p] - im[r] * re[p];
    }
  }
}
// X/Y accumulate, lane-bit qubit (each ordered pair counted -> net 2x already)
template<int MASK>
__device__ __forceinline__ void xys(int lane, const f2 (&re)[16], const f2 (&im)[16], f2& aX, f2& aY) {
  const float sgn = (lane & MASK) ? -1.f : 1.f;
#pragma unroll
  for (int r = 0; r < 16; ++r) {
    const f2 pr = shflx_f2<MASK>(re[r], lane);
    const f2 pi = shflx_f2<MASK>(im[r], lane);
    aX += re[r] * pr + im[r] * pi;
    aY += (re[r] * pi - im[r] * pr) * sgn;
  }
}

// ---------------- prep kernel: all weight-dependent transcendentals ----------------
// ws layout (float2): [0..69] gate table; [70..1093] rz1 per-amp (cos,sin);
//                     [1094..2117] rz2 per-amp (cos,sin)
__global__ void qae_prep(const float* __restrict__ w, float2* __restrict__ ws) {
  const int i = threadIdx.x;          // 0..1023
  if (i < 50) {                       // half-angle gate coefficients
    float s, c; __sincosf(0.5f * w[i], &s, &c);
    ws[i] = make_float2(c, s);
  } else if (i < 56) {                // FULL angle: Heisenberg output transform w[50..55]
    float s, c; __sincosf(w[i], &s, &c);
    ws[i] = make_float2(c, s);
  } else if (i < 60) {
    ws[i] = make_float2(1.f, 0.f);    // unused
  } else if (i < 70) {                // folded RY_b(layer1)+RY_c(layer2)
    const int q = i - 60;
    float s, c; __sincosf(0.5f * (w[20 + q] + w[30 + q]), &s, &c);
    ws[i] = make_float2(c, s);
  }
  // per-amplitude RZ phases: phi(i) = sum_b (bit b of i ? +.5 : -.5) * w[off + 9 - b]
  float p1 = 0.f, p2 = 0.f;
#pragma unroll
  for (int b = 0; b < 10; ++b) {
    const float sg = ((i >> b) & 1) ? 0.5f : -0.5f;
    p1 += sg * w[10 + 9 - b];
    p2 += sg * w[40 + 9 - b];
  }
  float s, c;
  __sincosf(p1, &s, &c); ws[70 + i]        = make_float2(c, s);
  __sincosf(p2, &s, &c); ws[70 + 1024 + i] = make_float2(c, s);
}

// LDS access at a byte offset (bases XOR compile-time constants)
#define STC(boff) (*reinterpret_cast<f2*>(reinterpret_cast<char*>(stc) + (boff)))

// ---------------- main kernel: 2 waves/block, 2 rows/wave, zero barriers ----------------
__global__ __launch_bounds__(128) void qae_main(const float* __restrict__ x,
                                                const float2* __restrict__ gt,
                                                float* __restrict__ out, int Btot) {
  __shared__ f2 lds[2 * 1024];          // 8KB wave-private regions
  const int tid  = threadIdx.x;
  const int lane = tid & 63;
  const int wid  = tid >> 6;
  const int gw   = blockIdx.x * 2 + wid;
  const int b0   = gw * 2, b1 = b0 + 1;
  if (b0 >= Btot) return;
  const bool has1 = (b1 < Btot);
  f2* stc = lds + (wid << 10);
  const float2* rz1 = gt + 70;
  const float2* rz2 = gt + 70 + 1024;

  // ---- XOR-linear LDS address bases (byte offsets), computed once per wave ----
  // All patterns factor as base(lane) ^ K(r): swzf and cnotL are GF(2)-linear and
  // (lane<<4)|r == (lane<<4)^r, (r<<6)|lane == (r<<6)^lane (disjoint bits).
  const int bA8  = swzf(lane << 4) << 3;          // writes at A: swz((lane<<4)|r) = this ^ (r<<3)
  const int sL8  = swzf(lane) << 3;               // B side: swz((r<<6)|lane) = swzf(r<<6)<<3 ^ this
  const int bCA8 = swzf(cnotL(lane << 4)) << 3;   // T2 read: ^ (swzf(cnotL(r))<<3)
  const int bCB8 = swzf(cnotL(lane)) << 3;        // T4 read: ^ (swzf(cnotL(r<<6))<<3)

  // Load 2 rows, layout A: g[r] = (row0[i], row1[i]), i = (lane<<4)|r; i>=768 zero.
  f2 g[16];
  f2 ss = (f2){0.f, 0.f};
  const float* x0 = x + (size_t)b0 * DIN;
  const float* x1 = x + (size_t)b1 * DIN;
#pragma unroll
  for (int t = 0; t < 4; ++t) {
    const int idx = lane * 16 + 4 * t;
    float4 va = make_float4(0.f, 0.f, 0.f, 0.f);
    float4 vb = make_float4(0.f, 0.f, 0.f, 0.f);
    if (idx < DIN) {
      va = *reinterpret_cast<const float4*>(x0 + idx);
      if (has1) vb = *reinterpret_cast<const float4*>(x1 + idx);
    }
    g[4*t+0] = (f2){va.x, vb.x}; g[4*t+1] = (f2){va.y, vb.y};
    g[4*t+2] = (f2){va.z, vb.z}; g[4*t+3] = (f2){va.w, vb.w};
#pragma unroll
    for (int k = 0; k < 4; ++k) ss += g[4*t+k] * g[4*t+k];
  }
  ss = wsum2(ss);
  const f2 inv = (f2){1.f / fmaxf(ss.x, 1e-16f), 1.f / fmaxf(ss.y, 1e-16f)};

  float2 cs;
  // ===== layer 1 RY round (w[0..9]) — REAL state, layout A: r bits 3..0 <-> q6..q9 =====
  cs = gt[6]; ry1<3>(g, cs.x, cs.y);
  cs = gt[7]; ry1<2>(g, cs.x, cs.y);
  cs = gt[8]; ry1<1>(g, cs.x, cs.y);
  cs = gt[9]; ry1<0>(g, cs.x, cs.y);
  cs = gt[4]; ry1_shfl<2>(lane, g, cs.x, cs.y);   // q4 <-> lane bit 1
  cs = gt[5]; ry1_shfl<1>(lane, g, cs.x, cs.y);   // q5 <-> lane bit 0

  // T1: A->B (real, rows travel inside the f2 cell)
#pragma unroll
  for (int r = 0; r < 16; ++r) STC(bA8 ^ (r << 3)) = g[r];
#pragma unroll
  for (int r = 0; r < 16; ++r) g[r] = STC((swzf(r << 6) << 3) ^ sL8);

  // B: r bits 3..0 <-> q0..q3
  cs = gt[0]; ry1<3>(g, cs.x, cs.y);
  cs = gt[1]; ry1<2>(g, cs.x, cs.y);
  cs = gt[2]; ry1<1>(g, cs.x, cs.y);
  cs = gt[3]; ry1<0>(g, cs.x, cs.y);

  // RZ1 (table): real -> complex, rows packed: re/im separate register files
  f2 re[16], im[16];
#pragma unroll
  for (int r = 0; r < 16; ++r) {
    const float2 t = rz1[(r << 6) | lane];
    re[r] = g[r] * t.x;
    im[r] = g[r] * t.y;
  }

  // T2: CNOT ring 1 fused into B->A transpose (two b64 passes through 8KB)
#pragma unroll
  for (int r = 0; r < 16; ++r) STC((swzf(r << 6) << 3) ^ sL8) = re[r];
#pragma unroll
  for (int r = 0; r < 16; ++r) re[r] = STC(bCA8 ^ (swzf(cnotL(r)) << 3));
#pragma unroll
  for (int r = 0; r < 16; ++r) STC((swzf(r << 6) << 3) ^ sL8) = im[r];
#pragma unroll
  for (int r = 0; r < 16; ++r) im[r] = STC(bCA8 ^ (swzf(cnotL(r)) << 3));

  // ===== combined RY round (folded, gt[60..69]), layout A =====
  cs = gt[66]; ry2<3>(re, im, cs.x, cs.y);
  cs = gt[67]; ry2<2>(re, im, cs.x, cs.y);
  cs = gt[68]; ry2<1>(re, im, cs.x, cs.y);
  cs = gt[69]; ry2<0>(re, im, cs.x, cs.y);
  cs = gt[64]; ry1_shfl<2>(lane, re, cs.x, cs.y); ry1_shfl<2>(lane, im, cs.x, cs.y);
  cs = gt[65]; ry1_shfl<1>(lane, re, cs.x, cs.y); ry1_shfl<1>(lane, im, cs.x, cs.y);

  // T3: A->B
#pragma unroll
  for (int r = 0; r < 16; ++r) STC(bA8 ^ (r << 3)) = re[r];
#pragma unroll
  for (int r = 0; r < 16; ++r) re[r] = STC((swzf(r << 6) << 3) ^ sL8);
#pragma unroll
  for (int r = 0; r < 16; ++r) STC(bA8 ^ (r << 3)) = im[r];
#pragma unroll
  for (int r = 0; r < 16; ++r) im[r] = STC((swzf(r << 6) << 3) ^ sL8);

  cs = gt[60]; ry2<3>(re, im, cs.x, cs.y);
  cs = gt[61]; ry2<2>(re, im, cs.x, cs.y);
  cs = gt[62]; ry2<1>(re, im, cs.x, cs.y);
  cs = gt[63]; ry2<0>(re, im, cs.x, cs.y);

  // RZ2 (table)
#pragma unroll
  for (int r = 0; r < 16; ++r) {
    const float2 t = rz2[(r << 6) | lane];
    const f2 nre = re[r] * t.x - im[r] * t.y;
    im[r] = re[r] * t.y + im[r] * t.x;
    re[r] = nre;
  }

  // T4: CNOT ring 2, gather read directly into layout B (final RY folded at output)
#pragma unroll
  for (int r = 0; r < 16; ++r) STC((swzf(r << 6) << 3) ^ sL8) = re[r];
#pragma unroll
  for (int r = 0; r < 16; ++r) re[r] = STC(bCB8 ^ (swzf(cnotL(r << 6)) << 3));
#pragma unroll
  for (int r = 0; r < 16; ++r) STC((swzf(r << 6) << 3) ^ sL8) = im[r];
#pragma unroll
  for (int r = 0; r < 16; ++r) im[r] = STC(bCB8 ^ (swzf(cnotL(r << 6)) << 3));

  // ===== expectation values (layout B), rows packed in f2 =====
  // acc order: [0..5]=X, [6..11]=Y, [12..17]=Z
  f2 a18[18];
#pragma unroll
  for (int k = 0; k < 12; ++k) a18[k] = (f2){0.f, 0.f};

  {
    f2 psum = (f2){0.f, 0.f};
    f2 z0 = (f2){0.f,0.f}, z1 = (f2){0.f,0.f}, z2 = (f2){0.f,0.f}, z3 = (f2){0.f,0.f};
#pragma unroll
    for (int r = 0; r < 16; ++r) {
      const f2 p = re[r] * re[r] + im[r] * im[r];
      psum += p;
      z0 += (r & 8) ? -p : p;
      z1 += (r & 4) ? -p : p;
      z2 += (r & 2) ? -p : p;
      z3 += (r & 1) ? -p : p;
    }
    a18[12] = z0; a18[13] = z1; a18[14] = z2; a18[15] = z3;
    a18[16] = ((lane >> 5) & 1) ? -psum : psum;   // Z q4
    a18[17] = ((lane >> 4) & 1) ? -psum : psum;   // Z q5
  }

  xyr<3>(re, im, a18[0], a18[6]);
  xyr<2>(re, im, a18[1], a18[7]);
  xyr<1>(re, im, a18[2], a18[8]);
  xyr<0>(re, im, a18[3], a18[9]);
  xys<32>(lane, re, im, a18[4], a18[10]);
  xys<16>(lane, re, im, a18[5], a18[11]);

  // --- distributed reduction: 2-step quad pre-reduce, then LDS combine ---
#pragma unroll
  for (int k = 0; k < 18; ++k) {
    f2 v = a18[k];
    v += dppf2<0xB1>(v);     // xor 1
    v += dppf2<0x4E>(v);     // xor 2  -> every lane in a quad holds the quad sum
    a18[k] = v;
  }
  float* red = reinterpret_cast<float*>(stc);     // reuse wave-private LDS (T4 done)
  if ((lane & 3) == 0) {
    const int q = lane >> 2;                      // quad id 0..15
    f2* redf2 = reinterpret_cast<f2*>(red);
#pragma unroll
    for (int k = 0; k < 18; ++k) redf2[q * 20 + k] = a18[k];
  }
  // Lanes 0..35: (c = row, j = observable). Sum 16 quad partials for own acc and
  // the Heisenberg partner (X<->Z), transform, store straight to out.
  if (lane < 36) {
    const int c  = (lane >= 18) ? 1 : 0;
    const int j  = lane - 18 * c;
    const int jq = (j < 6) ? j : ((j < 12) ? j - 6 : j - 12);
    const int jp = (j < 6) ? (j + 12) : ((j >= 12) ? (j - 12) : j);
    float S = 0.f, P = 0.f;
#pragma unroll
    for (int q = 0; q < 16; ++q) {
      S += red[(q * 20 + j ) * 2 + c];
      P += red[(q * 20 + jp) * 2 + c];
    }
    const float fac  = (jq < 4) ? 2.f : 1.f;      // xyr pairs once; xys twice
    const float2 fa  = gt[50 + jq];
    const float invc = c ? inv.y : inv.x;
    float o;
    if (j < 6)       o = (fac * S * fa.x + P * fa.y) * invc;        // X' = c*X + s*Z
    else if (j < 12) o = fac * S * invc;                            // Y' = Y
    else             o = (S * fa.x - fac * P * fa.y) * invc;        // Z' = c*Z - s*X
    if (c == 0 || has1) out[(size_t)(b0 + c) * 18 + j] = o;
  }
}

extern "C" void kernel_launch(void* const* d_in, const int* in_sizes, int n_in,
                              void* d_out, int out_size, void* d_ws, size_t ws_size,
                              hipStream_t stream) {
  const float* x = (const float*)d_in[0];
  const float* w = (const float*)d_in[1];
  float* out = (float*)d_out;
  float2* ws = (float2*)d_ws;
  const int B = in_sizes[0] / DIN;
  qae_prep<<<dim3(1), dim3(1024), 0, stream>>>(w, ws);
  const int grid = (B + 3) / 4;     // 2 waves/block x 2 rows/wave
  qae_main<<<dim3(grid), dim3(128), 0, stream>>>(x, (const float2*)ws, out, B);
}

// Round 12
// 100.105 us; speedup vs baseline: 1.3560x; 1.0158x over previous
//
#include <hip/hip_runtime.h>

#define DIN 768

typedef float f2 __attribute__((ext_vector_type(2)));
typedef int i2v __attribute__((ext_vector_type(2)));

#if __has_builtin(__builtin_amdgcn_permlane32_swap)
#define HAVE_PL32 1
#endif
#if __has_builtin(__builtin_amdgcn_permlane16_swap)
#define HAVE_PL16 1
#endif

__device__ __forceinline__ int f2i(float v) { return __builtin_bit_cast(int, v); }
__device__ __forceinline__ float i2f(int v) { return __builtin_bit_cast(float, v); }

// DPP ctrl: quad_perm xor1 = 0xB1 ; xor2 = 0x4E ; row_ror:4 = 0x124 ; row_ror:8 = 0x128
template<int CTRL>
__device__ __forceinline__ float dppf(float v) {
  const int i = f2i(v);
  return i2f(__builtin_amdgcn_update_dpp(i, i, CTRL, 0xF, 0xF, true));
}
template<int CTRL>
__device__ __forceinline__ f2 dppf2(f2 v) {
  f2 r; r.x = dppf<CTRL>(v.x); r.y = dppf<CTRL>(v.y); return r;
}

// Full 64-lane sum of both f2 components. Zero DS ops. (Used once, for sumsq.)
__device__ __forceinline__ f2 wsum2(f2 v) {
  v += dppf2<0xB1>(v);
  v += dppf2<0x4E>(v);
  v += dppf2<0x124>(v);
  v += dppf2<0x128>(v);
#ifdef HAVE_PL16
  { i2v rx = __builtin_amdgcn_permlane16_swap(f2i(v.x), f2i(v.x), false, false);
    i2v ry = __builtin_amdgcn_permlane16_swap(f2i(v.y), f2i(v.y), false, false);
    v.x = i2f(rx.x) + i2f(rx.y);
    v.y = i2f(ry.x) + i2f(ry.y); }
#else
  v.x += __shfl_xor(v.x, 16); v.y += __shfl_xor(v.y, 16);
#endif
#ifdef HAVE_PL32
  { i2v rx = __builtin_amdgcn_permlane32_swap(f2i(v.x), f2i(v.x), false, false);
    i2v ry = __builtin_amdgcn_permlane32_swap(f2i(v.y), f2i(v.y), false, false);
    v.x = i2f(rx.x) + i2f(rx.y);
    v.y = i2f(ry.x) + i2f(ry.y); }
#else
  v.x += __shfl_xor(v.x, 32); v.y += __shfl_xor(v.y, 32);
#endif
  return v;
}

// xor-shuffle of an f2, VALU-only for masks 1,2,16,32.
template<int MASK>
__device__ __forceinline__ f2 shflx_f2(f2 v, int lane) {
  f2 r;
  if constexpr (MASK == 1) {
    r = dppf2<0xB1>(v);
  } else if constexpr (MASK == 2) {
    r = dppf2<0x4E>(v);
  } else if constexpr (MASK == 16) {
#ifdef HAVE_PL16
    const i2v a = __builtin_amdgcn_permlane16_swap(f2i(v.x), f2i(v.x), false, false);
    const i2v b = __builtin_amdgcn_permlane16_swap(f2i(v.y), f2i(v.y), false, false);
    const bool hi = (lane >> 4) & 1;
    r.x = hi ? i2f(a.x) : i2f(a.y);
    r.y = hi ? i2f(b.x) : i2f(b.y);
#else
    r.x = __shfl_xor(v.x, 16); r.y = __shfl_xor(v.y, 16);
#endif
  } else if constexpr (MASK == 32) {
#ifdef HAVE_PL32
    const i2v a = __builtin_amdgcn_permlane32_swap(f2i(v.x), f2i(v.x), false, false);
    const i2v b = __builtin_amdgcn_permlane32_swap(f2i(v.y), f2i(v.y), false, false);
    const bool lo = lane < 32;
    r.x = lo ? i2f(a.y) : i2f(a.x);
    r.y = lo ? i2f(b.y) : i2f(b.x);
#else
    r.x = __shfl_xor(v.x, 32); r.y = __shfl_xor(v.y, 32);
#endif
  } else {
    r.x = __shfl_xor(v.x, MASK); r.y = __shfl_xor(v.y, MASK);
  }
  return r;
}

// LDS address swizzle (GF(2)-linear: swzf(a^b) = swzf(a)^swzf(b))
__device__ __forceinline__ int swzf(int i) { return i ^ ((i >> 4) & 31); }

// Composite gather map of the CNOT ring CNOT(0,1)..CNOT(9,0): Final[i] = In[cnotL(i)]
// GF(2)-linear: every output bit is an XOR of input bits.
__device__ __forceinline__ int cnotL(int i) {
  const int b9 = (i >> 9) & 1;
  const int b8 = (i >> 8) & 1;
  const int b0 = i & 1;
  return ((i ^ (i >> 1)) & 0xFF) | ((b8 ^ b9 ^ b0) << 8) | ((b9 ^ b0) << 9);
}

// RY on a 16-reg component array (rows packed in f2). Real 2x2 acts per component.
template<int RB>
__device__ __forceinline__ void ry1(f2 (&a)[16], float c, float s) {
#pragma unroll
  for (int r = 0; r < 16; ++r) {
    if (!(r & (1 << RB))) {
      const int p = r | (1 << RB);
      const f2 a0 = a[r], a1 = a[p];
      a[r] = a0 * c - a1 * s;
      a[p] = a1 * c + a0 * s;
    }
  }
}
template<int RB>
__device__ __forceinline__ void ry2(f2 (&re)[16], f2 (&im)[16], float c, float s) {
  ry1<RB>(re, c, s);
  ry1<RB>(im, c, s);
}
template<int MASK>
__device__ __forceinline__ void ry1_shfl(int lane, f2 (&a)[16], float c, float s) {
  const float ss = (lane & MASK) ? s : -s;
#pragma unroll
  for (int r = 0; r < 16; ++r) {
    const f2 p = shflx_f2<MASK>(a[r], lane);
    a[r] = a[r] * c + p * ss;
  }
}

// X/Y accumulate, register-pair qubit (each unordered pair once -> fac 2 at output)
template<int RB>
__device__ __forceinline__ void xyr(const f2 (&re)[16], const f2 (&im)[16], f2& aX, f2& aY) {
#pragma unroll
  for (int r = 0; r < 16; ++r) {
    if (!(r & (1 << RB))) {
      const int p = r | (1 << RB);
      aX += re[r] * re[p] + im[r] * im[p];
      aY += re[r] * im[p] - im[r] * re[p];
    }
  }
}
// X/Y accumulate, lane-bit qubit (each ordered pair counted -> net 2x already)
template<int MASK>
__device__ __forceinline__ void xys(int lane, const f2 (&re)[16], const f2 (&im)[16], f2& aX, f2& aY) {
  const float sgn = (lane & MASK) ? -1.f : 1.f;
#pragma unroll
  for (int r = 0; r < 16; ++r) {
    const f2 pr = shflx_f2<MASK>(re[r], lane);
    const f2 pi = shflx_f2<MASK>(im[r], lane);
    aX += re[r] * pr + im[r] * pi;
    aY += (re[r] * pi - im[r] * pr) * sgn;
  }
}

// ---------------- prep kernel: all weight-dependent transcendentals ----------------
// ws layout (float2): [0..69] gate table; [70..1093] rz1 per-amp (cos,sin);
//                     [1094..2117] rz2 per-amp (cos,sin)
__global__ void qae_prep(const float* __restrict__ w, float2* __restrict__ ws) {
  const int i = threadIdx.x;          // 0..1023
  if (i < 50) {                       // half-angle gate coefficients
    float s, c; __sincosf(0.5f * w[i], &s, &c);
    ws[i] = make_float2(c, s);
  } else if (i < 56) {                // FULL angle: Heisenberg output transform w[50..55]
    float s, c; __sincosf(w[i], &s, &c);
    ws[i] = make_float2(c, s);
  } else if (i < 60) {
    ws[i] = make_float2(1.f, 0.f);    // unused
  } else if (i < 70) {                // folded RY_b(layer1)+RY_c(layer2)
    const int q = i - 60;
    float s, c; __sincosf(0.5f * (w[20 + q] + w[30 + q]), &s, &c);
    ws[i] = make_float2(c, s);
  }
  // per-amplitude RZ phases: phi(i) = sum_b (bit b of i ? +.5 : -.5) * w[off + 9 - b]
  float p1 = 0.f, p2 = 0.f;
#pragma unroll
  for (int b = 0; b < 10; ++b) {
    const float sg = ((i >> b) & 1) ? 0.5f : -0.5f;
    p1 += sg * w[10 + 9 - b];
    p2 += sg * w[40 + 9 - b];
  }
  float s, c;
  __sincosf(p1, &s, &c); ws[70 + i]        = make_float2(c, s);
  __sincosf(p2, &s, &c); ws[70 + 1024 + i] = make_float2(c, s);
}

// LDS access at a byte offset (bases XOR compile-time constants)
#define STC(boff) (*reinterpret_cast<f2*>(reinterpret_cast<char*>(stc) + (boff)))

// -------- main kernel: ONE wave per block (8KB LDS), 2 rows/wave, zero barriers --------
__global__ __launch_bounds__(64) void qae_main(const float* __restrict__ x,
                                               const float2* __restrict__ gt,
                                               float* __restrict__ out, int Btot) {
  __shared__ f2 stc[1024];              // 8KB, wave-private by construction
  const int lane = threadIdx.x;
  const int b0   = blockIdx.x * 2, b1 = b0 + 1;
  const bool has1 = (b1 < Btot);
  const float2* rz1 = gt + 70;
  const float2* rz2 = gt + 70 + 1024;

  // ---- XOR-linear LDS address bases (byte offsets), computed once per wave ----
  // All patterns factor as base(lane) ^ K(r): swzf and cnotL are GF(2)-linear and
  // (lane<<4)|r == (lane<<4)^r, (r<<6)|lane == (r<<6)^lane (disjoint bits).
  const int bA8  = swzf(lane << 4) << 3;          // writes at A: swz((lane<<4)|r) = this ^ (r<<3)
  const int sL8  = swzf(lane) << 3;               // B side: swz((r<<6)|lane) = swzf(r<<6)<<3 ^ this
  const int bCA8 = swzf(cnotL(lane << 4)) << 3;   // T2 read: ^ (swzf(cnotL(r))<<3)
  const int bCB8 = swzf(cnotL(lane)) << 3;        // T4 read: ^ (swzf(cnotL(r<<6))<<3)

  // Load 2 rows, layout A: g[r] = (row0[i], row1[i]), i = (lane<<4)|r; i>=768 zero.
  f2 g[16];
  f2 ss = (f2){0.f, 0.f};
  const float* x0 = x + (size_t)b0 * DIN;
  const float* x1 = x + (size_t)b1 * DIN;
#pragma unroll
  for (int t = 0; t < 4; ++t) {
    const int idx = lane * 16 + 4 * t;
    float4 va = make_float4(0.f, 0.f, 0.f, 0.f);
    float4 vb = make_float4(0.f, 0.f, 0.f, 0.f);
    if (idx < DIN) {
      va = *reinterpret_cast<const float4*>(x0 + idx);
      if (has1) vb = *reinterpret_cast<const float4*>(x1 + idx);
    }
    g[4*t+0] = (f2){va.x, vb.x}; g[4*t+1] = (f2){va.y, vb.y};
    g[4*t+2] = (f2){va.z, vb.z}; g[4*t+3] = (f2){va.w, vb.w};
#pragma unroll
    for (int k = 0; k < 4; ++k) ss += g[4*t+k] * g[4*t+k];
  }
  ss = wsum2(ss);
  const f2 inv = (f2){1.f / fmaxf(ss.x, 1e-16f), 1.f / fmaxf(ss.y, 1e-16f)};

  float2 cs;
  // ===== layer 1 RY round (w[0..9]) — REAL state, layout A: r bits 3..0 <-> q6..q9 =====
  cs = gt[6]; ry1<3>(g, cs.x, cs.y);
  cs = gt[7]; ry1<2>(g, cs.x, cs.y);
  cs = gt[8]; ry1<1>(g, cs.x, cs.y);
  cs = gt[9]; ry1<0>(g, cs.x, cs.y);
  cs = gt[4]; ry1_shfl<2>(lane, g, cs.x, cs.y);   // q4 <-> lane bit 1
  cs = gt[5]; ry1_shfl<1>(lane, g, cs.x, cs.y);   // q5 <-> lane bit 0

  // T1: A->B (real, rows travel inside the f2 cell)
#pragma unroll
  for (int r = 0; r < 16; ++r) STC(bA8 ^ (r << 3)) = g[r];
#pragma unroll
  for (int r = 0; r < 16; ++r) g[r] = STC((swzf(r << 6) << 3) ^ sL8);

  // B: r bits 3..0 <-> q0..q3
  cs = gt[0]; ry1<3>(g, cs.x, cs.y);
  cs = gt[1]; ry1<2>(g, cs.x, cs.y);
  cs = gt[2]; ry1<1>(g, cs.x, cs.y);
  cs = gt[3]; ry1<0>(g, cs.x, cs.y);

  // RZ1 (table): real -> complex, rows packed: re/im separate register files
  f2 re[16], im[16];
#pragma unroll
  for (int r = 0; r < 16; ++r) {
    const float2 t = rz1[(r << 6) | lane];
    re[r] = g[r] * t.x;
    im[r] = g[r] * t.y;
  }

  // T2: CNOT ring 1 fused into B->A transpose (two b64 passes through 8KB)
#pragma unroll
  for (int r = 0; r < 16; ++r) STC((swzf(r << 6) << 3) ^ sL8) = re[r];
#pragma unroll
  for (int r = 0; r < 16; ++r) re[r] = STC(bCA8 ^ (swzf(cnotL(r)) << 3));
#pragma unroll
  for (int r = 0; r < 16; ++r) STC((swzf(r << 6) << 3) ^ sL8) = im[r];
#pragma unroll
  for (int r = 0; r < 16; ++r) im[r] = STC(bCA8 ^ (swzf(cnotL(r)) << 3));

  // ===== combined RY round (folded, gt[60..69]), layout A =====
  cs = gt[66]; ry2<3>(re, im, cs.x, cs.y);
  cs = gt[67]; ry2<2>(re, im, cs.x, cs.y);
  cs = gt[68]; ry2<1>(re, im, cs.x, cs.y);
  cs = gt[69]; ry2<0>(re, im, cs.x, cs.y);
  cs = gt[64]; ry1_shfl<2>(lane, re, cs.x, cs.y); ry1_shfl<2>(lane, im, cs.x, cs.y);
  cs = gt[65]; ry1_shfl<1>(lane, re, cs.x, cs.y); ry1_shfl<1>(lane, im, cs.x, cs.y);

  // T3: A->B
#pragma unroll
  for (int r = 0; r < 16; ++r) STC(bA8 ^ (r << 3)) = re[r];
#pragma unroll
  for (int r = 0; r < 16; ++r) re[r] = STC((swzf(r << 6) << 3) ^ sL8);
#pragma unroll
  for (int r = 0; r < 16; ++r) STC(bA8 ^ (r << 3)) = im[r];
#pragma unroll
  for (int r = 0; r < 16; ++r) im[r] = STC((swzf(r << 6) << 3) ^ sL8);

  cs = gt[60]; ry2<3>(re, im, cs.x, cs.y);
  cs = gt[61]; ry2<2>(re, im, cs.x, cs.y);
  cs = gt[62]; ry2<1>(re, im, cs.x, cs.y);
  cs = gt[63]; ry2<0>(re, im, cs.x, cs.y);

  // RZ2 (table)
#pragma unroll
  for (int r = 0; r < 16; ++r) {
    const float2 t = rz2[(r << 6) | lane];
    const f2 nre = re[r] * t.x - im[r] * t.y;
    im[r] = re[r] * t.y + im[r] * t.x;
    re[r] = nre;
  }

  // T4: CNOT ring 2, gather read directly into layout B (final RY folded at output)
#pragma unroll
  for (int r = 0; r < 16; ++r) STC((swzf(r << 6) << 3) ^ sL8) = re[r];
#pragma unroll
  for (int r = 0; r < 16; ++r) re[r] = STC(bCB8 ^ (swzf(cnotL(r << 6)) << 3));
#pragma unroll
  for (int r = 0; r < 16; ++r) STC((swzf(r << 6) << 3) ^ sL8) = im[r];
#pragma unroll
  for (int r = 0; r < 16; ++r) im[r] = STC(bCB8 ^ (swzf(cnotL(r << 6)) << 3));

  // ===== expectation values (layout B), rows packed in f2 =====
  // acc order: [0..5]=X, [6..11]=Y, [12..17]=Z
  f2 a18[18];
#pragma unroll
  for (int k = 0; k < 12; ++k) a18[k] = (f2){0.f, 0.f};

  {
    f2 psum = (f2){0.f, 0.f};
    f2 z0 = (f2){0.f,0.f}, z1 = (f2){0.f,0.f}, z2 = (f2){0.f,0.f}, z3 = (f2){0.f,0.f};
#pragma unroll
    for (int r = 0; r < 16; ++r) {
      const f2 p = re[r] * re[r] + im[r] * im[r];
      psum += p;
      z0 += (r & 8) ? -p : p;
      z1 += (r & 4) ? -p : p;
      z2 += (r & 2) ? -p : p;
      z3 += (r & 1) ? -p : p;
    }
    a18[12] = z0; a18[13] = z1; a18[14] = z2; a18[15] = z3;
    a18[16] = ((lane >> 5) & 1) ? -psum : psum;   // Z q4
    a18[17] = ((lane >> 4) & 1) ? -psum : psum;   // Z q5
  }

  xyr<3>(re, im, a18[0], a18[6]);
  xyr<2>(re, im, a18[1], a18[7]);
  xyr<1>(re, im, a18[2], a18[8]);
  xyr<0>(re, im, a18[3], a18[9]);
  xys<32>(lane, re, im, a18[4], a18[10]);
  xys<16>(lane, re, im, a18[5], a18[11]);

  // --- distributed reduction: 2-step quad pre-reduce, then LDS combine ---
#pragma unroll
  for (int k = 0; k < 18; ++k) {
    f2 v = a18[k];
    v += dppf2<0xB1>(v);     // xor 1
    v += dppf2<0x4E>(v);     // xor 2  -> every lane in a quad holds the quad sum
    a18[k] = v;
  }
  float* red = reinterpret_cast<float*>(stc);     // reuse wave-private LDS (T4 done)
  if ((lane & 3) == 0) {
    const int q = lane >> 2;                      // quad id 0..15
    f2* redf2 = reinterpret_cast<f2*>(red);
#pragma unroll
    for (int k = 0; k < 18; ++k) redf2[q * 20 + k] = a18[k];
  }
  // Lanes 0..35: (c = row, j = observable). Sum 16 quad partials for own acc and
  // the Heisenberg partner (X<->Z), transform, store straight to out.
  if (lane < 36) {
    const int c  = (lane >= 18) ? 1 : 0;
    const int j  = lane - 18 * c;
    const int jq = (j < 6) ? j : ((j < 12) ? j - 6 : j - 12);
    const int jp = (j < 6) ? (j + 12) : ((j >= 12) ? (j - 12) : j);
    float S = 0.f, P = 0.f;
#pragma unroll
    for (int q = 0; q < 16; ++q) {
      S += red[(q * 20 + j ) * 2 + c];
      P += red[(q * 20 + jp) * 2 + c];
    }
    const float fac  = (jq < 4) ? 2.f : 1.f;      // xyr pairs once; xys twice
    const float2 fa  = gt[50 + jq];
    const float invc = c ? inv.y : inv.x;
    float o;
    if (j < 6)       o = (fac * S * fa.x + P * fa.y) * invc;        // X' = c*X + s*Z
    else if (j < 12) o = fac * S * invc;                            // Y' = Y
    else             o = (S * fa.x - fac * P * fa.y) * invc;        // Z' = c*Z - s*X
    if (c == 0 || has1) out[(size_t)(b0 + c) * 18 + j] = o;
  }
}

extern "C" void kernel_launch(void* const* d_in, const int* in_sizes, int n_in,
                              void* d_out, int out_size, void* d_ws, size_t ws_size,
                              hipStream_t stream) {
  const float* x = (const float*)d_in[0];
  const float* w = (const float*)d_in[1];
  float* out = (float*)d_out;
  float2* ws = (float2*)d_ws;
  const int B = in_sizes[0] / DIN;
  qae_prep<<<dim3(1), dim3(1024), 0, stream>>>(w, ws);
  const int grid = (B + 1) / 2;     // 1 wave/block, 2 rows/wave
  qae_main<<<dim3(grid), dim3(64), 0, stream>>>(x, (const float2*)ws, out, B);
}